// Round 7
// baseline (99.078 us; speedup 1.0000x reference)
//
#include <hip/hip_runtime.h>

#define M_NODES 100000
#define BM 64
#define NT ((M_NODES + BM - 1) / BM)   // 1563
#define GRID 256                        // persistent, 1 block/CU

typedef float  f32x4  __attribute__((ext_vector_type(4)));
typedef short  bf16x8 __attribute__((ext_vector_type(8)));

#define AS1 __attribute__((address_space(1)))
#define AS3 __attribute__((address_space(3)))

static __device__ __forceinline__ unsigned short f2bf(float f) {
  union { float f; unsigned int u; } v; v.f = f;
  return (unsigned short)((v.u + 0x7FFFu + ((v.u >> 16) & 1u)) >> 16);  // RNE
}

static __device__ __forceinline__ unsigned int cvt2(float lo, float hi) {
  unsigned int r;
  asm("v_cvt_pk_bf16_f32 %0, %1, %2" : "=v"(r) : "v"(lo), "v"(hi));
  return r;
}

// ---------------------------------------------------------------------------
// prep: W[k][n] f32 -> phys bf16 image, n-major 512B rows, 16B slots
// XOR-swizzled:  img[n*256 + (((k>>3)^(n&7))<<3) + (k&7)] = bf16(W[k][n])
// (b-frag read: lane l15=n, slot kk*4+lhi -> phys slot ^(n&7): conflict-free)
// ---------------------------------------------------------------------------
__global__ void prep_w(const float* __restrict__ W1, const float* __restrict__ W2,
                       unsigned short* __restrict__ U1, unsigned short* __restrict__ U2) {
  int b = blockIdx.x;                        // 512 blocks x 256 threads
  const float* W = (b < 256) ? W1 : W2;
  unsigned short* U = (b < 256) ? U1 : U2;
  int n = b & 255, k = threadIdx.x;
  U[n * 256 + (((k >> 3) ^ (n & 7)) << 3) + (k & 7)] = f2bf(W[k * 256 + n]);
}

// ---------------------------------------------------------------------------
// Wave-autonomous W-stationary streaming pass.
// 256 blocks x 256 thr (4 waves), 1 block/CU. LDS 160KB = W image (128KB,
// staged once, ONE barrier ever) + XH transpose buf (32KB, 4 wave-PRIVATE
// 16-row x 512B regions -> no cross-wave sync in steady state at all).
// Per tile (64 rows, wave owns 16):
//   PASS1: X(t) regs -> cvt -> swizzled ds_write -> a-frags; issue X(t+1)
//          row-loads (full-GEMM latency cover); H out = bias+relu bf16 linear.
//   PASS2: H staged direct global_load_lds (linear dest + preswizzled per-lane
//          src), in-order counted vmcnt(63) guard (never 0); out f32 stores.
// MFMA: wave = 16 rows x 256 cols = 16 nf x 8 kk 16x16x32 per tile.
// ---------------------------------------------------------------------------
template <int PASS>
__global__ __launch_bounds__(256, 1)
void mlp_pass(const float* __restrict__ Xf,
              const unsigned short* __restrict__ Hin,
              const unsigned short* __restrict__ Wimg,
              const float* __restrict__ bias,
              unsigned short* __restrict__ Hout,
              float* __restrict__ Cout)
{
  __shared__ unsigned short lds[81920];       // 160 KB
  unsigned short* Wl = lds;                   // 65536 ushorts (128 KB)
  unsigned short* XH = lds + 65536;           // 16384 ushorts (32 KB): [64][256]

  const int tid  = threadIdx.x;
  const int lane = tid & 63;
  const int l15  = lane & 15;
  const int lhi  = lane >> 4;                 // 0..3
  const int w    = tid >> 6;                  // 0..3
  const int r0   = w * 16;                    // wave-private local row base

  // ---- one-time: W image -> LDS (linear copy; image is pre-swizzled) -----
  #pragma unroll 4
  for (int i = 0; i < 32; ++i) {
    int c = i * 4 + w;                        // 128 chunks x 1KB
    __builtin_amdgcn_global_load_lds(
        (const AS1 unsigned int*)(const void*)(Wimg + c * 512 + lane * 8),
        (AS3 unsigned int*)(void*)(Wl + c * 512), 16, 0, 0);
  }
  float vb[16];
  #pragma unroll
  for (int nf = 0; nf < 16; ++nf) vb[nf] = bias[nf * 16 + l15];
  asm volatile("s_waitcnt vmcnt(0)" ::: "memory");
  __builtin_amdgcn_sched_barrier(0);
  __builtin_amdgcn_s_barrier();               // the only barrier

  if (PASS == 1) {
    // ---- pass 1: H = relu(X @ W1 + b1) -----------------------------------
    f32x4 xr[16];                             // one 16-row slab in regs
    auto loadX = [&](int t) {
      #pragma unroll
      for (int i = 0; i < 16; ++i) {
        int grow = t * BM + r0 + i;
        f32x4 v = {0.f, 0.f, 0.f, 0.f};
        if (grow < M_NODES) v = *(const f32x4*)(Xf + (size_t)grow * 256 + lane * 4);
        xr[i] = v;
      }
    };
    loadX(blockIdx.x);

    #pragma unroll 1
    for (int t = blockIdx.x; t < NT; t += GRID) {
      // cvt + swizzled ds_write of X(t)  (auto counted-vmcnt wait on xr)
      #pragma unroll
      for (int i = 0; i < 16; ++i) {
        unsigned long long pk =
            ((unsigned long long)cvt2(xr[i][2], xr[i][3]) << 32) | cvt2(xr[i][0], xr[i][1]);
        *(unsigned long long*)(XH + (r0 + i) * 256 +
                               (((lane >> 1) ^ (i & 7)) << 3) + (lane & 1) * 4) = pk;
      }
      loadX(t + GRID);                        // next slab in flight over whole GEMM
      asm volatile("s_waitcnt lgkmcnt(0)" ::: "memory");
      __builtin_amdgcn_sched_barrier(0);

      bf16x8 af[8];
      #pragma unroll
      for (int kk = 0; kk < 8; ++kk)
        af[kk] = *(const bf16x8*)(XH + (r0 + l15) * 256 +
                                  (((kk * 4 + lhi) ^ (l15 & 7)) << 3));
      f32x4 acc[16];
      #pragma unroll
      for (int nf = 0; nf < 16; ++nf) acc[nf] = f32x4{0.f, 0.f, 0.f, 0.f};
      #pragma unroll
      for (int nf = 0; nf < 16; ++nf) {
        int n = nf * 16 + l15;
        const unsigned short* wrow = Wl + n * 256;
        #pragma unroll
        for (int kk = 0; kk < 8; ++kk) {
          bf16x8 bf_ = *(const bf16x8*)(wrow + (((kk * 4 + lhi) ^ (n & 7)) << 3));
          acc[nf] = __builtin_amdgcn_mfma_f32_16x16x32_bf16(af[kk], bf_, acc[nf], 0, 0, 0);
        }
      }
      // epilogue: bias + relu -> bf16 H image (linear rows)
      #pragma unroll
      for (int nf = 0; nf < 16; ++nf) {
        #pragma unroll
        for (int rg = 0; rg < 4; ++rg) {
          int grow = t * BM + r0 + lhi * 4 + rg;
          if (grow < M_NODES) {
            float v = fmaxf(acc[nf][rg] + vb[nf], 0.f);
            __builtin_nontemporal_store(f2bf(v),
                Hout + (size_t)grow * 256 + nf * 16 + l15);
          }
        }
      }
    }
  } else {
    // ---- pass 2: out = H @ W2 + b2 ---------------------------------------
    auto stageH = [&](int t) {                // 8 x 1KB into wave-private region
      #pragma unroll
      for (int i = 0; i < 8; ++i) {
        int rl = t * BM + r0 + 2 * i + (lane >> 5);
        __builtin_amdgcn_global_load_lds(
            (const AS1 unsigned int*)(const void*)(
                Hin + (size_t)rl * 256 + (((lane & 31) ^ (rl & 7)) << 3)),
            (AS3 unsigned int*)(void*)(XH + (r0 + 2 * i) * 256), 16, 0, 0);
      }
    };
    stageH(blockIdx.x);
    asm volatile("s_waitcnt vmcnt(0)" ::: "memory");
    __builtin_amdgcn_sched_barrier(0);

    #pragma unroll 1
    for (int t = blockIdx.x; t < NT; t += GRID) {
      bf16x8 af[8];
      #pragma unroll
      for (int kk = 0; kk < 8; ++kk)
        af[kk] = *(const bf16x8*)(XH + (r0 + l15) * 256 +
                                  (((kk * 4 + lhi) ^ (l15 & 7)) << 3));
      asm volatile("s_waitcnt lgkmcnt(0)" ::: "memory");   // reads done before
      __builtin_amdgcn_sched_barrier(0);                    // stage overwrites
      if (t + GRID < NT) stageH(t + GRID);

      f32x4 acc[16];
      #pragma unroll
      for (int nf = 0; nf < 16; ++nf) acc[nf] = f32x4{0.f, 0.f, 0.f, 0.f};
      #pragma unroll
      for (int nf = 0; nf < 16; ++nf) {
        int n = nf * 16 + l15;
        const unsigned short* wrow = Wl + n * 256;
        #pragma unroll
        for (int kk = 0; kk < 8; ++kk) {
          bf16x8 bf_ = *(const bf16x8*)(wrow + (((kk * 4 + lhi) ^ (n & 7)) << 3));
          acc[nf] = __builtin_amdgcn_mfma_f32_16x16x32_bf16(af[kk], bf_, acc[nf], 0, 0, 0);
        }
      }
      #pragma unroll
      for (int nf = 0; nf < 16; ++nf) {
        #pragma unroll
        for (int rg = 0; rg < 4; ++rg) {
          int grow = t * BM + r0 + lhi * 4 + rg;
          if (grow < M_NODES)
            __builtin_nontemporal_store(acc[nf][rg] + vb[nf],
                Cout + (size_t)grow * 256 + nf * 16 + l15);
        }
      }
      // in-order counted guard: stage(t+GRID)'s 8 loads are older than the 64
      // stores just issued -> outstanding<=63 implies stage retired. Never 0.
      asm volatile("s_waitcnt vmcnt(63)" ::: "memory");
      __builtin_amdgcn_sched_barrier(0);
    }
  }
}

// ---------------------------------------------------------------------------
extern "C" void kernel_launch(void* const* d_in, const int* in_sizes, int n_in,
                              void* d_out, int out_size, void* d_ws, size_t ws_size,
                              hipStream_t stream) {
  const float* emb = (const float*)d_in[0];
  const float* W1  = (const float*)d_in[1];
  const float* b1  = (const float*)d_in[2];
  const float* W2  = (const float*)d_in[3];
  const float* b2  = (const float*)d_in[4];
  // d_in[5] = prop_edge_index: unused at ChebConv K=1.
  float* out = (float*)d_out;

  unsigned short* U1   = (unsigned short*)d_ws;  // 65536 ushorts (128 KB)
  unsigned short* U2   = U1 + 65536;             // 128 KB
  unsigned short* Himg = U2 + 65536;             // 100032*256 ushorts = 51.2 MB

  prep_w<<<512, 256, 0, stream>>>(W1, W2, U1, U2);
  mlp_pass<1><<<GRID, 256, 0, stream>>>(emb, nullptr, U1, b1, Himg, nullptr);
  mlp_pass<2><<<GRID, 256, 0, stream>>>(nullptr, Himg, U2, b2, nullptr, out);
}